// Round 13
// baseline (97.462 us; speedup 1.0000x reference)
//
#include <hip/hip_runtime.h>
#include <hip/hip_bf16.h>

#define BB 4
#define NN 10000
#define EE 320000
#define HH 8
#define NHQ 2                 // head halves
#define NRQ 2                 // src ranges per batch
#define SEGR (NN / NRQ)       // 5000 segments per range
#define NSLICE 16             // edge slices -> grid = 4*2*2*16 = 256 = 1 block/CU
#define ESL (EE / NSLICE)     // 20000 edges per slice
#define UU 4                  // edges batched per thread (MLP)
#define SCALE 16777216.0f     // 2^24 fixed-point
#define INVSC (1.0f / 16777216.0f)
#define LDB 36                // LDS leading dim (ushorts): 72 B stride -> ~2-way banks

typedef float f4 __attribute__((ext_vector_type(4)));
typedef short s8v __attribute__((ext_vector_type(8)));
typedef unsigned short u16x8 __attribute__((ext_vector_type(8)));
typedef unsigned short u16x4 __attribute__((ext_vector_type(4)));

__device__ __forceinline__ unsigned short f2bf(float f) {
  unsigned int u = __float_as_uint(f);
  u += 0x7FFFu + ((u >> 16) & 1u);
  return (unsigned short)(u >> 16);
}
__device__ __forceinline__ float bf2f(unsigned short s) {
  return __uint_as_float(((unsigned int)s) << 16);
}
__device__ __forceinline__ unsigned int ordf(float f) {
  unsigned int u = __float_as_uint(f);
  return (u & 0x80000000u) ? ~u : (u | 0x80000000u);
}
__device__ __forceinline__ float unordf(unsigned int u) {
  unsigned int b = (u & 0x80000000u) ? (u & 0x7FFFFFFFu) : ~u;
  return __uint_as_float(b);
}

// ------- W transpose + bf16 convert: Wt[n][k] = bf16(W[k][n]); also zeroes mxbuf -------
__global__ __launch_bounds__(256) void k_transpose(const float* __restrict__ W,
                                                   unsigned short* __restrict__ Wt,
                                                   unsigned int* __restrict__ mxbuf) {
  if (blockIdx.x == 0 && blockIdx.y == 0 && threadIdx.x < 16) mxbuf[threadIdx.x] = 0u;
  __shared__ float tile[64][65];
  const int n0 = blockIdx.x * 64, k0 = blockIdx.y * 64;
  for (int i = threadIdx.x; i < 4096; i += 256) {
    int kk = i >> 6, nn = i & 63;
    tile[kk][nn] = W[(size_t)(k0 + kk) * 256 + n0 + nn];
  }
  __syncthreads();
  for (int i = threadIdx.x; i < 4096; i += 256) {
    int nn = i >> 6, kk = i & 63;
    Wt[(size_t)(n0 + nn) * 256 + (k0 + kk)] = f2bf(tile[kk][nn]);
  }
}

// ---- GEMM + fused score epilogue: 32-row tiles, grid 1250, A-prefetch, padded LDS ----
__global__ __launch_bounds__(256, 6) void k_gemm(const float* __restrict__ x,
                                                 const unsigned short* __restrict__ Wt,
                                                 const float* __restrict__ a,
                                                 float* __restrict__ wx,
                                                 unsigned short* __restrict__ ssbf,
                                                 unsigned short* __restrict__ sdbf,
                                                 unsigned int* __restrict__ mxbuf) {
  __shared__ unsigned short sA[32][LDB];   // [row][k]
  __shared__ unsigned short sB[256][LDB];  // [col][k] (= W^T)
  __shared__ unsigned int lmx[16];
  const int tid = threadIdx.x;
  const int lane = tid & 63;
  const int wv = tid >> 6;
  const int row0 = blockIdx.x << 5;        // 32 rows per block
  const int fr = lane & 15;
  const int fg = lane >> 4;
  f4 acc[2][4] = {};
  const int ar = tid >> 3;                 // 0..31 staging row
  const int ak = (tid & 7) << 2;           // 0,4,..28 staging k (4 f32 each)
  if (tid < 16) lmx[tid] = 0u;

  const float* xp0 = x + (size_t)(row0 + ar) * 256 + ak;
  f4 v = *(const f4*)xp0;                  // prefetched A chunk for k0=0
  for (int k0 = 0; k0 < 256; k0 += 32) {
    // stage prefetched A (f32 -> bf16)
    u16x4 av;
    av[0] = f2bf(v[0]); av[1] = f2bf(v[1]); av[2] = f2bf(v[2]); av[3] = f2bf(v[3]);
    *(u16x4*)&sA[ar][ak] = av;
    // stage B tile (bf16 W^T, L2-hot)
#pragma unroll
    for (int j = 0; j < 4; ++j) {
      int ci = tid + (j << 8);
      int col = ci >> 2;
      int ks = (ci & 3) << 3;
      *(u16x8*)&sB[col][ks] = *(const u16x8*)(Wt + (size_t)col * 256 + k0 + ks);
    }
    __syncthreads();
    if (k0 < 224) v = *(const f4*)(xp0 + k0 + 32);   // prefetch next A chunk
    s8v afr[2], bfr[4];
#pragma unroll
    for (int m = 0; m < 2; ++m) afr[m] = *(const s8v*)&sA[m * 16 + fr][fg << 3];
#pragma unroll
    for (int n = 0; n < 4; ++n) bfr[n] = *(const s8v*)&sB[wv * 64 + n * 16 + fr][fg << 3];
#pragma unroll
    for (int m = 0; m < 2; ++m)
#pragma unroll
      for (int n = 0; n < 4; ++n)
        acc[m][n] = __builtin_amdgcn_mfma_f32_16x16x32_bf16(afr[m], bfr[n], acc[m][n], 0, 0, 0);
    __syncthreads();
  }
  // C store: D[row][col], col = lane&15, row = (lane>>4)*4 + q
#pragma unroll
  for (int m = 0; m < 2; ++m)
#pragma unroll
    for (int n = 0; n < 4; ++n) {
      int col = wv * 64 + n * 16 + fr;
#pragma unroll
      for (int q = 0; q < 4; ++q) {
        int row = row0 + m * 16 + fg * 4 + q;
        wx[(size_t)row * 256 + col] = acc[m][n][q];
      }
    }
  // fused scores: wave wv owns heads {2wv, 2wv+1}; butterfly leaves sums in ALL lanes
  const float as0 = a[fr], as1 = a[16 + fr];
  const float ad0 = a[32 + fr], ad1 = a[48 + fr];
  unsigned mp0 = 0u, mp1 = 0u, md0 = 0u, md1 = 0u;   // ordf running maxes
#pragma unroll
  for (int m = 0; m < 2; ++m)
#pragma unroll
    for (int q = 0; q < 4; ++q) {
      float p0 = acc[m][0][q] * as0 + acc[m][1][q] * as1;
      float p1 = acc[m][2][q] * as0 + acc[m][3][q] * as1;
      float d0 = acc[m][0][q] * ad0 + acc[m][1][q] * ad1;
      float d1 = acc[m][2][q] * ad0 + acc[m][3][q] * ad1;
#pragma unroll
      for (int msk = 1; msk <= 8; msk <<= 1) {
        p0 += __shfl_xor(p0, msk);
        p1 += __shfl_xor(p1, msk);
        d0 += __shfl_xor(d0, msk);
        d1 += __shfl_xor(d1, msk);
      }
      mp0 = max(mp0, ordf(p0)); mp1 = max(mp1, ordf(p1));
      md0 = max(md0, ordf(d0)); md1 = max(md1, ordf(d1));
      if (fr == 0) {
        int row = row0 + m * 16 + fg * 4 + q;
        unsigned sspk = (unsigned)f2bf(p0) | ((unsigned)f2bf(p1) << 16);
        unsigned sdpk = (unsigned)f2bf(d0) | ((unsigned)f2bf(d1) << 16);
        ((unsigned*)ssbf)[(size_t)row * 4 + wv] = sspk;
        ((unsigned*)sdbf)[(size_t)row * 4 + wv] = sdpk;
      }
    }
  if (fr == 0) {
    atomicMax(&lmx[wv * 2],     mp0);
    atomicMax(&lmx[wv * 2 + 1], mp1);
    atomicMax(&lmx[8 + wv * 2],     md0);
    atomicMax(&lmx[8 + wv * 2 + 1], md1);
  }
  __syncthreads();
  if (tid < 16 && lmx[tid]) atomicMax(&mxbuf[tid], lmx[tid]);
}

// ---- LDS-privatized denom binning: block = (batch, head-half, src-range, slice) ----
// Per edge: ONE scattered 8-B dst gather (src half-row from 40 KB LDS stage).
// hist = u32 fixed-point, native ds_add_u32. LDS = 80K hist + 40K stage = 120 KB.
__global__ __launch_bounds__(1024) void k_bin(const int* __restrict__ edge,
                                              const unsigned short* __restrict__ ssbf,
                                              const unsigned short* __restrict__ sdbf,
                                              const unsigned int* __restrict__ mxbuf,
                                              unsigned int* __restrict__ partial) {
  extern __shared__ unsigned int ldsu[];
  unsigned int* hist = ldsu;                      // [4][SEGR] u32
  uint2* stg = (uint2*)(ldsu + 4 * SEGR);         // [SEGR] 8-B src half-rows
  const int blk = blockIdx.x;                     // ((b*2+hq)*2+rq)*NSLICE + r
  const int r = blk & (NSLICE - 1);
  const int c = blk / NSLICE;
  const int rq = c & 1;
  const int hq = (c >> 1) & 1;
  const int b = c >> 2;
  const int tid = threadIdx.x;
  const int lo = rq * SEGR;
  for (int i = tid; i < 4 * SEGR; i += 1024) hist[i] = 0u;
  const unsigned short* ssb = ssbf + ((size_t)b * NN + lo) * 8 + hq * 4;
  for (int i = tid; i < SEGR; i += 1024) stg[i] = *(const uint2*)(ssb + (size_t)i * 8);
  __syncthreads();
  float MH[4];
#pragma unroll
  for (int j = 0; j < 4; ++j)
    MH[j] = fmaxf(unordf(mxbuf[hq * 4 + j]) + unordf(mxbuf[8 + hq * 4 + j]), 0.f);
  const int* eps = edge + (size_t)b * 2 * EE + r * ESL;
  const int* epd = eps + EE;
  const unsigned short* sdb = sdbf + (size_t)b * NN * 8 + hq * 4;
  for (int base = 0; base < ESL; base += UU * 1024) {
    int ls4[UU], dst4[UU];
    bool v4[UU];
#pragma unroll
    for (int u = 0; u < UU; ++u) {
      int i = base + tid + u * 1024;
      bool inb = i < ESL;
      int s = inb ? eps[i] : 0;
      dst4[u] = inb ? epd[i] : 0;
      int ls = s - lo;
      v4[u] = inb && ((unsigned)ls < (unsigned)SEGR);
      ls4[u] = ls;
    }
    uint2 du4[UU];
#pragma unroll
    for (int u = 0; u < UU; ++u)
      if (v4[u]) du4[u] = *(const uint2*)(sdb + (size_t)dst4[u] * 8);
#pragma unroll
    for (int u = 0; u < UU; ++u) {
      if (v4[u]) {
        uint2 su = stg[ls4[u]];
        float t0 = __uint_as_float(su.x << 16) + __uint_as_float(du4[u].x << 16);
        float t1 = __uint_as_float(su.x & 0xFFFF0000u) + __uint_as_float(du4[u].x & 0xFFFF0000u);
        float t2 = __uint_as_float(su.y << 16) + __uint_as_float(du4[u].y << 16);
        float t3 = __uint_as_float(su.y & 0xFFFF0000u) + __uint_as_float(du4[u].y & 0xFFFF0000u);
        t0 = t0 >= 0.f ? t0 : 0.2f * t0;
        t1 = t1 >= 0.f ? t1 : 0.2f * t1;
        t2 = t2 >= 0.f ? t2 : 0.2f * t2;
        t3 = t3 >= 0.f ? t3 : 0.2f * t3;
        atomicAdd(&hist[0 * SEGR + ls4[u]], (unsigned)(__expf(t0 - MH[0]) * SCALE + 0.5f));
        atomicAdd(&hist[1 * SEGR + ls4[u]], (unsigned)(__expf(t1 - MH[1]) * SCALE + 0.5f));
        atomicAdd(&hist[2 * SEGR + ls4[u]], (unsigned)(__expf(t2 - MH[2]) * SCALE + 0.5f));
        atomicAdd(&hist[3 * SEGR + ls4[u]], (unsigned)(__expf(t3 - MH[3]) * SCALE + 0.5f));
      }
    }
  }
  __syncthreads();
  f4* pout = (f4*)(partial + (size_t)blk * (4 * SEGR));
  const f4* lin = (const f4*)hist;
  for (int i = tid; i < SEGR; i += 1024) pout[i] = lin[i];
}

// ---- reduce NSLICE slice-partials (u32) -> denom (bf16 half-rows), exact int sums ----
__global__ __launch_bounds__(256) void k_reduce(const unsigned int* __restrict__ partial,
                                                unsigned short* __restrict__ dnbf) {
  const int t = blockIdx.x * 256 + threadIdx.x;   // BB*NHQ*NRQ*SEGR = 80000
  if (t >= BB * NHQ * NRQ * SEGR) return;
  const int ls = t % SEGR;
  const int c = t / SEGR;                         // ((b*2+hq)*2+rq)
  const unsigned int* pp = partial + (size_t)c * NSLICE * (4 * SEGR);
  unsigned long long s[4] = {0, 0, 0, 0};
#pragma unroll 4
  for (int r = 0; r < NSLICE; ++r)
#pragma unroll
    for (int h = 0; h < 4; ++h)
      s[h] += pp[(size_t)r * (4 * SEGR) + h * SEGR + ls];
  const int rq = c & 1, hq = (c >> 1) & 1, b = c >> 2;
  uint2 pk;
  pk.x = (unsigned)f2bf((float)s[0] * INVSC) | ((unsigned)f2bf((float)s[1] * INVSC) << 16);
  pk.y = (unsigned)f2bf((float)s[2] * INVSC) | ((unsigned)f2bf((float)s[3] * INVSC) << 16);
  *(uint2*)(dnbf + ((size_t)b * NN + rq * SEGR + ls) * 8 + hq * 4) = pk;
}

// ---------------- finalize: att = exp(el - M) / denom ----------------
__global__ __launch_bounds__(256) void k_fin(const int* __restrict__ edge,
                                             const unsigned short* __restrict__ ssbf,
                                             const unsigned short* __restrict__ sdbf,
                                             const unsigned short* __restrict__ dnbf,
                                             const unsigned int* __restrict__ mxbuf,
                                             float* __restrict__ att) {
  const int idx = blockIdx.x * 256 + threadIdx.x;
  const int b = idx / EE;
  const int e = idx - b * EE;
  const int src = edge[(size_t)b * 2 * EE + e];
  const int dst = edge[(size_t)b * 2 * EE + EE + e];
  const size_t seg = (size_t)b * NN + src;
  float MM[8];
#pragma unroll
  for (int j = 0; j < 8; ++j)
    MM[j] = fmaxf(unordf(mxbuf[j]) + unordf(mxbuf[8 + j]), 0.f);
  u16x8 ss = *(const u16x8*)(ssbf + seg * 8);
  u16x8 sd = *(const u16x8*)(sdbf + ((size_t)b * NN + dst) * 8);
  u16x8 dn = *(const u16x8*)(dnbf + seg * 8);
  f4 o0, o1;
#pragma unroll
  for (int j = 0; j < 4; ++j) {
    float t0 = bf2f(ss[j]) + bf2f(sd[j]);
    t0 = t0 >= 0.f ? t0 : 0.2f * t0;
    float t1 = bf2f(ss[4 + j]) + bf2f(sd[4 + j]);
    t1 = t1 >= 0.f ? t1 : 0.2f * t1;
    float n0 = __expf(t0 - MM[j]);
    float n1 = __expf(t1 - MM[4 + j]);
    o0[j] = n0 / fmaxf(bf2f(dn[j]), n0);
    o1[j] = n1 / fmaxf(bf2f(dn[4 + j]), n1);
  }
  f4* op = (f4*)(att + (size_t)idx * 8);
  op[0] = o0;
  op[1] = o1;
}

extern "C" void kernel_launch(void* const* d_in, const int* in_sizes, int n_in,
                              void* d_out, int out_size, void* d_ws, size_t ws_size,
                              hipStream_t stream) {
  const float* x = (const float*)d_in[0];
  const int* edge = (const int*)d_in[1];
  const float* W = (const float*)d_in[2];
  const float* a = (const float*)d_in[3];

  float* att = (float*)d_out;                       // (B,E,H) = 10,240,000 f32 = 40.96 MB
  float* wx = att + (size_t)BB * EE * HH;           // (B,N,256) = 10,240,000 f32

  // partial histograms live in the att output region (dead until k_fin):
  // 256 blocks * 80000 B = 20.48 MB < 40.96 MB.
  unsigned int* partial = (unsigned int*)att;

  char* ws = (char*)d_ws;
  unsigned short* Wt = (unsigned short*)ws;                 // 128 KiB
  unsigned short* ssbf = (unsigned short*)(ws + 131072);    // 320000 u16
  unsigned short* sdbf = ssbf + 320000;                     // 320000 u16
  unsigned short* dnbf = sdbf + 320000;                     // 320000 u16
  unsigned int* mxbuf = (unsigned int*)(dnbf + 320000);     // 16 u32

  hipFuncSetAttribute((const void*)k_bin, hipFuncAttributeMaxDynamicSharedMemorySize,
                      4 * SEGR * 4 + SEGR * 8);

  k_transpose<<<dim3(4, 4), 256, 0, stream>>>(W, Wt, mxbuf);
  k_gemm<<<1250, 256, 0, stream>>>(x, Wt, a, wx, ssbf, sdbf, mxbuf);
  k_bin<<<BB * NHQ * NRQ * NSLICE, 1024, 4 * SEGR * 4 + SEGR * 8, stream>>>(edge, ssbf, sdbf, mxbuf, partial);
  k_reduce<<<(BB * NHQ * NRQ * SEGR + 255) / 256, 256, 0, stream>>>(partial, dnbf);
  k_fin<<<5000, 256, 0, stream>>>(edge, ssbf, sdbf, dnbf, mxbuf, att);
}

// Round 14
// 93.322 us; speedup vs baseline: 1.0444x; 1.0444x over previous
//
#include <hip/hip_runtime.h>
#include <hip/hip_bf16.h>

#define BB 4
#define NN 10000
#define EE 320000
#define HH 8
#define NHQ 2                 // head halves
#define NRQ 2                 // src ranges per batch
#define SEGR (NN / NRQ)       // 5000 segments per range
#define NSLICE 16             // edge slices -> grid = 4*2*2*16 = 256 = 1 block/CU
#define ESL (EE / NSLICE)     // 20000 edges per slice
#define UU 4                  // edges batched per thread (MLP)
#define SCALE 16777216.0f     // 2^24 fixed-point
#define INVSC (1.0f / 16777216.0f)

typedef float f4 __attribute__((ext_vector_type(4)));
typedef short s8v __attribute__((ext_vector_type(8)));
typedef unsigned short u16x8 __attribute__((ext_vector_type(8)));

__device__ __forceinline__ unsigned short f2bf(float f) {
  unsigned int u = __float_as_uint(f);
  u += 0x7FFFu + ((u >> 16) & 1u);
  return (unsigned short)(u >> 16);
}
__device__ __forceinline__ float bf2f(unsigned short s) {
  return __uint_as_float(((unsigned int)s) << 16);
}
__device__ __forceinline__ unsigned int ordf(float f) {
  unsigned int u = __float_as_uint(f);
  return (u & 0x80000000u) ? ~u : (u | 0x80000000u);
}
__device__ __forceinline__ float unordf(unsigned int u) {
  unsigned int b = (u & 0x80000000u) ? (u & 0x7FFFFFFFu) : ~u;
  return __uint_as_float(b);
}

// ------- W transpose + bf16 convert: Wt[n][k] = bf16(W[k][n]); also zeroes mxbuf -------
__global__ __launch_bounds__(256) void k_transpose(const float* __restrict__ W,
                                                   unsigned short* __restrict__ Wt,
                                                   unsigned int* __restrict__ mxbuf) {
  if (blockIdx.x == 0 && blockIdx.y == 0 && threadIdx.x < 16) mxbuf[threadIdx.x] = 0u;
  __shared__ float tile[64][65];
  const int n0 = blockIdx.x * 64, k0 = blockIdx.y * 64;
  for (int i = threadIdx.x; i < 4096; i += 256) {
    int kk = i >> 6, nn = i & 63;
    tile[kk][nn] = W[(size_t)(k0 + kk) * 256 + n0 + nn];
  }
  __syncthreads();
  for (int i = threadIdx.x; i < 4096; i += 256) {
    int nn = i >> 6, kk = i & 63;
    Wt[(size_t)(n0 + nn) * 256 + (k0 + kk)] = f2bf(tile[kk][nn]);
  }
}

// ---- GEMM v3: B-half staged ONCE (XOR-swizzled), barrier-free K loop, wave = 16x128 strip.
// grid = 626 x 512 thr (8 waves). LDS 64 KB -> 2 blocks/CU = 16 streaming waves/CU.
__global__ __launch_bounds__(512, 4) void k_gemm(const float* __restrict__ x,
                                                 const unsigned short* __restrict__ Wt,
                                                 const float* __restrict__ a,
                                                 float* __restrict__ wx,
                                                 unsigned short* __restrict__ ssbf,
                                                 unsigned short* __restrict__ sdbf,
                                                 unsigned int* __restrict__ mxbuf) {
  extern __shared__ char dyn[];
  unsigned short (*sB)[256] = (unsigned short(*)[256])dyn;   // [128][256]
  unsigned int* lmx = (unsigned int*)(dyn + 128 * 256 * 2);  // [16]
  const int tid = threadIdx.x;
  const int wv = tid >> 6;
  const int lane = tid & 63;
  const int fr = lane & 15;
  const int fg = lane >> 4;
  const int ch = blockIdx.x & 1;                 // col half
  const int strip = (blockIdx.x >> 1) * 8 + wv;  // 16-row strip id, 0..2503
  if (tid < 16) lmx[tid] = 0u;
  // stage B half cols [ch*128, ch*128+128): 4096 u16x8 chunks, XOR-swizzled k-chunks
#pragma unroll
  for (int p = 0; p < 8; ++p) {
    int q = p * 512 + tid;
    int c = q >> 5;                 // 0..127
    int kcc = q & 31;               // k-chunk
    *(u16x8*)&sB[c][(kcc ^ (c & 7)) << 3] =
        *(const u16x8*)(Wt + (size_t)(ch * 128 + c) * 256 + (kcc << 3));
  }
  __syncthreads();
  if (strip < 2500) {
    const float* ap = x + (size_t)(strip * 16 + fr) * 256 + (fg << 3);
    f4 v0 = *(const f4*)ap;
    f4 v1 = *(const f4*)(ap + 4);
    f4 acc[8] = {};
    const int sw = fr & 7;
#pragma unroll
    for (int k0 = 0; k0 < 256; k0 += 32) {
      u16x8 av;
      av[0] = f2bf(v0[0]); av[1] = f2bf(v0[1]); av[2] = f2bf(v0[2]); av[3] = f2bf(v0[3]);
      av[4] = f2bf(v1[0]); av[5] = f2bf(v1[1]); av[6] = f2bf(v1[2]); av[7] = f2bf(v1[3]);
      s8v afr = *(s8v*)&av;
      if (k0 < 224) {
        v0 = *(const f4*)(ap + k0 + 32);
        v1 = *(const f4*)(ap + k0 + 36);
      }
      const int kb = k0 >> 3;
#pragma unroll
      for (int n = 0; n < 8; ++n) {
        s8v bfr = *(const s8v*)&sB[n * 16 + fr][((kb + fg) ^ sw) << 3];
        acc[n] = __builtin_amdgcn_mfma_f32_16x16x32_bf16(afr, bfr, acc[n], 0, 0, 0);
      }
    }
    // wx store: D[row][col], col = lane&15 (+n*16+ch*128), row = fg*4+q
    const size_t rb = (size_t)strip * 16;
#pragma unroll
    for (int n = 0; n < 8; ++n) {
      int col = ch * 128 + n * 16 + fr;
#pragma unroll
      for (int q = 0; q < 4; ++q)
        wx[(rb + fg * 4 + q) * 256 + col] = acc[n][q];
    }
    // fused scores: this wave covers heads ch*4 .. ch*4+3
    const float as0 = a[fr], as1 = a[16 + fr];
    const float ad0 = a[32 + fr], ad1 = a[48 + fr];
#pragma unroll
    for (int j = 0; j < 4; ++j) {
      unsigned mp = 0u, md = 0u;
#pragma unroll
      for (int q = 0; q < 4; ++q) {
        float p = acc[2 * j][q] * as0 + acc[2 * j + 1][q] * as1;
        float d = acc[2 * j][q] * ad0 + acc[2 * j + 1][q] * ad1;
#pragma unroll
        for (int m = 1; m <= 8; m <<= 1) {
          p += __shfl_xor(p, m);
          d += __shfl_xor(d, m);
        }
        mp = max(mp, ordf(p));
        md = max(md, ordf(d));
        if (fr == 0) {
          size_t row = rb + fg * 4 + q;
          ssbf[row * 8 + ch * 4 + j] = f2bf(p);
          sdbf[row * 8 + ch * 4 + j] = f2bf(d);
        }
      }
      mp = max(mp, (unsigned)__shfl_xor((int)mp, 16));
      mp = max(mp, (unsigned)__shfl_xor((int)mp, 32));
      md = max(md, (unsigned)__shfl_xor((int)md, 16));
      md = max(md, (unsigned)__shfl_xor((int)md, 32));
      if (lane == 0) {
        atomicMax(&lmx[ch * 4 + j], mp);
        atomicMax(&lmx[8 + ch * 4 + j], md);
      }
    }
  }
  __syncthreads();
  if (tid < 16 && lmx[tid]) atomicMax(&mxbuf[tid], lmx[tid]);
}

// ---- LDS-privatized denom binning: block = (batch, head-half, src-range, slice) ----
__global__ __launch_bounds__(1024) void k_bin(const int* __restrict__ edge,
                                              const unsigned short* __restrict__ ssbf,
                                              const unsigned short* __restrict__ sdbf,
                                              const unsigned int* __restrict__ mxbuf,
                                              unsigned int* __restrict__ partial) {
  extern __shared__ unsigned int ldsu[];
  unsigned int* hist = ldsu;                      // [4][SEGR] u32
  uint2* stg = (uint2*)(ldsu + 4 * SEGR);         // [SEGR] 8-B src half-rows
  const int blk = blockIdx.x;                     // ((b*2+hq)*2+rq)*NSLICE + r
  const int r = blk & (NSLICE - 1);
  const int c = blk / NSLICE;
  const int rq = c & 1;
  const int hq = (c >> 1) & 1;
  const int b = c >> 2;
  const int tid = threadIdx.x;
  const int lo = rq * SEGR;
  for (int i = tid; i < 4 * SEGR; i += 1024) hist[i] = 0u;
  const unsigned short* ssb = ssbf + ((size_t)b * NN + lo) * 8 + hq * 4;
  for (int i = tid; i < SEGR; i += 1024) stg[i] = *(const uint2*)(ssb + (size_t)i * 8);
  __syncthreads();
  float MH[4];
#pragma unroll
  for (int j = 0; j < 4; ++j)
    MH[j] = fmaxf(unordf(mxbuf[hq * 4 + j]) + unordf(mxbuf[8 + hq * 4 + j]), 0.f);
  const int* eps = edge + (size_t)b * 2 * EE + r * ESL;
  const int* epd = eps + EE;
  const unsigned short* sdb = sdbf + (size_t)b * NN * 8 + hq * 4;
  for (int base = 0; base < ESL; base += UU * 1024) {
    int ls4[UU], dst4[UU];
    bool v4[UU];
#pragma unroll
    for (int u = 0; u < UU; ++u) {
      int i = base + tid + u * 1024;
      bool inb = i < ESL;
      int s = inb ? eps[i] : 0;
      dst4[u] = inb ? epd[i] : 0;
      int ls = s - lo;
      v4[u] = inb && ((unsigned)ls < (unsigned)SEGR);
      ls4[u] = ls;
    }
    uint2 du4[UU];
#pragma unroll
    for (int u = 0; u < UU; ++u)
      if (v4[u]) du4[u] = *(const uint2*)(sdb + (size_t)dst4[u] * 8);
#pragma unroll
    for (int u = 0; u < UU; ++u) {
      if (v4[u]) {
        uint2 su = stg[ls4[u]];
        float t0 = __uint_as_float(su.x << 16) + __uint_as_float(du4[u].x << 16);
        float t1 = __uint_as_float(su.x & 0xFFFF0000u) + __uint_as_float(du4[u].x & 0xFFFF0000u);
        float t2 = __uint_as_float(su.y << 16) + __uint_as_float(du4[u].y << 16);
        float t3 = __uint_as_float(su.y & 0xFFFF0000u) + __uint_as_float(du4[u].y & 0xFFFF0000u);
        t0 = t0 >= 0.f ? t0 : 0.2f * t0;
        t1 = t1 >= 0.f ? t1 : 0.2f * t1;
        t2 = t2 >= 0.f ? t2 : 0.2f * t2;
        t3 = t3 >= 0.f ? t3 : 0.2f * t3;
        atomicAdd(&hist[0 * SEGR + ls4[u]], (unsigned)(__expf(t0 - MH[0]) * SCALE + 0.5f));
        atomicAdd(&hist[1 * SEGR + ls4[u]], (unsigned)(__expf(t1 - MH[1]) * SCALE + 0.5f));
        atomicAdd(&hist[2 * SEGR + ls4[u]], (unsigned)(__expf(t2 - MH[2]) * SCALE + 0.5f));
        atomicAdd(&hist[3 * SEGR + ls4[u]], (unsigned)(__expf(t3 - MH[3]) * SCALE + 0.5f));
      }
    }
  }
  __syncthreads();
  f4* pout = (f4*)(partial + (size_t)blk * (4 * SEGR));
  const f4* lin = (const f4*)hist;
  for (int i = tid; i < SEGR; i += 1024) pout[i] = lin[i];
}

// ---- reduce NSLICE slice-partials (u32) -> denom (bf16 half-rows), exact int sums ----
__global__ __launch_bounds__(256) void k_reduce(const unsigned int* __restrict__ partial,
                                                unsigned short* __restrict__ dnbf) {
  const int t = blockIdx.x * 256 + threadIdx.x;   // BB*NHQ*NRQ*SEGR = 80000
  if (t >= BB * NHQ * NRQ * SEGR) return;
  const int ls = t % SEGR;
  const int c = t / SEGR;                         // ((b*2+hq)*2+rq)
  const unsigned int* pp = partial + (size_t)c * NSLICE * (4 * SEGR);
  unsigned long long s[4] = {0, 0, 0, 0};
#pragma unroll 4
  for (int r = 0; r < NSLICE; ++r)
#pragma unroll
    for (int h = 0; h < 4; ++h)
      s[h] += pp[(size_t)r * (4 * SEGR) + h * SEGR + ls];
  const int rq = c & 1, hq = (c >> 1) & 1, b = c >> 2;
  uint2 pk;
  pk.x = (unsigned)f2bf((float)s[0] * INVSC) | ((unsigned)f2bf((float)s[1] * INVSC) << 16);
  pk.y = (unsigned)f2bf((float)s[2] * INVSC) | ((unsigned)f2bf((float)s[3] * INVSC) << 16);
  *(uint2*)(dnbf + ((size_t)b * NN + rq * SEGR + ls) * 8 + hq * 4) = pk;
}

// ---------------- finalize: att = exp(el - M) / denom ----------------
__global__ __launch_bounds__(256) void k_fin(const int* __restrict__ edge,
                                             const unsigned short* __restrict__ ssbf,
                                             const unsigned short* __restrict__ sdbf,
                                             const unsigned short* __restrict__ dnbf,
                                             const unsigned int* __restrict__ mxbuf,
                                             float* __restrict__ att) {
  const int idx = blockIdx.x * 256 + threadIdx.x;
  const int b = idx / EE;
  const int e = idx - b * EE;
  const int src = edge[(size_t)b * 2 * EE + e];
  const int dst = edge[(size_t)b * 2 * EE + EE + e];
  const size_t seg = (size_t)b * NN + src;
  float MM[8];
#pragma unroll
  for (int j = 0; j < 8; ++j)
    MM[j] = fmaxf(unordf(mxbuf[j]) + unordf(mxbuf[8 + j]), 0.f);
  u16x8 ss = *(const u16x8*)(ssbf + seg * 8);
  u16x8 sd = *(const u16x8*)(sdbf + ((size_t)b * NN + dst) * 8);
  u16x8 dn = *(const u16x8*)(dnbf + seg * 8);
  f4 o0, o1;
#pragma unroll
  for (int j = 0; j < 4; ++j) {
    float t0 = bf2f(ss[j]) + bf2f(sd[j]);
    t0 = t0 >= 0.f ? t0 : 0.2f * t0;
    float t1 = bf2f(ss[4 + j]) + bf2f(sd[4 + j]);
    t1 = t1 >= 0.f ? t1 : 0.2f * t1;
    float n0 = __expf(t0 - MM[j]);
    float n1 = __expf(t1 - MM[4 + j]);
    o0[j] = n0 / fmaxf(bf2f(dn[j]), n0);
    o1[j] = n1 / fmaxf(bf2f(dn[4 + j]), n1);
  }
  f4* op = (f4*)(att + (size_t)idx * 8);
  op[0] = o0;
  op[1] = o1;
}

extern "C" void kernel_launch(void* const* d_in, const int* in_sizes, int n_in,
                              void* d_out, int out_size, void* d_ws, size_t ws_size,
                              hipStream_t stream) {
  const float* x = (const float*)d_in[0];
  const int* edge = (const int*)d_in[1];
  const float* W = (const float*)d_in[2];
  const float* a = (const float*)d_in[3];

  float* att = (float*)d_out;                       // (B,E,H) = 10,240,000 f32 = 40.96 MB
  float* wx = att + (size_t)BB * EE * HH;           // (B,N,256) = 10,240,000 f32

  // partial histograms live in the att output region (dead until k_fin):
  // 256 blocks * 80000 B = 20.48 MB < 40.96 MB.
  unsigned int* partial = (unsigned int*)att;

  char* ws = (char*)d_ws;
  unsigned short* Wt = (unsigned short*)ws;                 // 128 KiB
  unsigned short* ssbf = (unsigned short*)(ws + 131072);    // 320000 u16
  unsigned short* sdbf = ssbf + 320000;                     // 320000 u16
  unsigned short* dnbf = sdbf + 320000;                     // 320000 u16
  unsigned int* mxbuf = (unsigned int*)(dnbf + 320000);     // 16 u32

  const int gemmLds = 128 * 256 * 2 + 64;
  hipFuncSetAttribute((const void*)k_gemm, hipFuncAttributeMaxDynamicSharedMemorySize, gemmLds);
  hipFuncSetAttribute((const void*)k_bin, hipFuncAttributeMaxDynamicSharedMemorySize,
                      4 * SEGR * 4 + SEGR * 8);

  k_transpose<<<dim3(4, 4), 256, 0, stream>>>(W, Wt, mxbuf);
  k_gemm<<<626, 512, gemmLds, stream>>>(x, Wt, a, wx, ssbf, sdbf, mxbuf);
  k_bin<<<BB * NHQ * NRQ * NSLICE, 1024, 4 * SEGR * 4 + SEGR * 8, stream>>>(edge, ssbf, sdbf, mxbuf, partial);
  k_reduce<<<(BB * NHQ * NRQ * SEGR + 255) / 256, 256, 0, stream>>>(partial, dnbf);
  k_fin<<<5000, 256, 0, stream>>>(edge, ssbf, sdbf, dnbf, mxbuf, att);
}

// Round 15
// 93.014 us; speedup vs baseline: 1.0478x; 1.0033x over previous
//
#include <hip/hip_runtime.h>
#include <hip/hip_bf16.h>

#define BB 4
#define NN 10000
#define EE 320000
#define HH 8
#define NHQ 2                 // head halves
#define NRQ 2                 // src ranges per batch
#define SEGR (NN / NRQ)       // 5000 segments per range
#define NSLICE 16             // edge slices -> grid = 4*2*2*16 = 256 = 1 block/CU
#define ESL (EE / NSLICE)     // 20000 edges per slice
#define UU 4                  // edges batched per thread (MLP)
#define SCALE 16777216.0f     // 2^24 fixed-point
#define INVSC (1.0f / 16777216.0f)

typedef float f4 __attribute__((ext_vector_type(4)));
typedef short s8v __attribute__((ext_vector_type(8)));
typedef unsigned short u16x8 __attribute__((ext_vector_type(8)));

__device__ __forceinline__ unsigned short f2bf(float f) {
  unsigned int u = __float_as_uint(f);
  u += 0x7FFFu + ((u >> 16) & 1u);
  return (unsigned short)(u >> 16);
}
__device__ __forceinline__ float bf2f(unsigned short s) {
  return __uint_as_float(((unsigned int)s) << 16);
}
__device__ __forceinline__ unsigned int ordf(float f) {
  unsigned int u = __float_as_uint(f);
  return (u & 0x80000000u) ? ~u : (u | 0x80000000u);
}
__device__ __forceinline__ float unordf(unsigned int u) {
  unsigned int b = (u & 0x80000000u) ? (u & 0x7FFFFFFFu) : ~u;
  return __uint_as_float(b);
}

// ------- W transpose + bf16 convert: Wt[n][k] = bf16(W[k][n]); also zeroes mxbuf -------
__global__ __launch_bounds__(256) void k_transpose(const float* __restrict__ W,
                                                   unsigned short* __restrict__ Wt,
                                                   unsigned int* __restrict__ mxbuf) {
  if (blockIdx.x == 0 && blockIdx.y == 0 && threadIdx.x < 16) mxbuf[threadIdx.x] = 0u;
  __shared__ float tile[64][65];
  const int n0 = blockIdx.x * 64, k0 = blockIdx.y * 64;
  for (int i = threadIdx.x; i < 4096; i += 256) {
    int kk = i >> 6, nn = i & 63;
    tile[kk][nn] = W[(size_t)(k0 + kk) * 256 + n0 + nn];
  }
  __syncthreads();
  for (int i = threadIdx.x; i < 4096; i += 256) {
    int nn = i >> 6, kk = i & 63;
    Wt[(size_t)(n0 + nn) * 256 + (k0 + kk)] = f2bf(tile[kk][nn]);
  }
}

// ---- GEMM v4: B-half staged ONCE (XOR-swizzled), barrier-free K loop, wave = 16x128 strip,
// ---- FULL A-strip issued upfront (16 independent f4 loads = 16 KB/wave in flight). ----
__global__ __launch_bounds__(512, 3) void k_gemm(const float* __restrict__ x,
                                                 const unsigned short* __restrict__ Wt,
                                                 const float* __restrict__ a,
                                                 float* __restrict__ wx,
                                                 unsigned short* __restrict__ ssbf,
                                                 unsigned short* __restrict__ sdbf,
                                                 unsigned int* __restrict__ mxbuf) {
  extern __shared__ char dyn[];
  unsigned short (*sB)[256] = (unsigned short(*)[256])dyn;   // [128][256]
  unsigned int* lmx = (unsigned int*)(dyn + 128 * 256 * 2);  // [16]
  const int tid = threadIdx.x;
  const int wv = tid >> 6;
  const int lane = tid & 63;
  const int fr = lane & 15;
  const int fg = lane >> 4;
  const int ch = blockIdx.x & 1;                 // col half
  const int strip = (blockIdx.x >> 1) * 8 + wv;  // 16-row strip id, 0..2503
  if (tid < 16) lmx[tid] = 0u;
  // stage B half cols [ch*128, ch*128+128): 4096 u16x8 chunks, XOR-swizzled k-chunks
#pragma unroll
  for (int p = 0; p < 8; ++p) {
    int q = p * 512 + tid;
    int c = q >> 5;                 // 0..127
    int kcc = q & 31;               // k-chunk
    *(u16x8*)&sB[c][(kcc ^ (c & 7)) << 3] =
        *(const u16x8*)(Wt + (size_t)(ch * 128 + c) * 256 + (kcc << 3));
  }
  __syncthreads();
  if (strip < 2500) {
    const float* ap = x + (size_t)(strip * 16 + fr) * 256 + (fg << 3);
    // issue the ENTIRE A strip now: 16 independent 16-B loads, 256 B/lane in flight
    f4 va[16];
#pragma unroll
    for (int i = 0; i < 8; ++i) {
      va[2 * i]     = *(const f4*)(ap + i * 32);
      va[2 * i + 1] = *(const f4*)(ap + i * 32 + 4);
    }
    f4 acc[8] = {};
    const int sw = fr & 7;
#pragma unroll
    for (int i = 0; i < 8; ++i) {
      f4 v0 = va[2 * i], v1 = va[2 * i + 1];
      u16x8 av;
      av[0] = f2bf(v0[0]); av[1] = f2bf(v0[1]); av[2] = f2bf(v0[2]); av[3] = f2bf(v0[3]);
      av[4] = f2bf(v1[0]); av[5] = f2bf(v1[1]); av[6] = f2bf(v1[2]); av[7] = f2bf(v1[3]);
      s8v afr = *(s8v*)&av;
      const int kb = i * 4;
#pragma unroll
      for (int n = 0; n < 8; ++n) {
        s8v bfr = *(const s8v*)&sB[n * 16 + fr][((kb + fg) ^ sw) << 3];
        acc[n] = __builtin_amdgcn_mfma_f32_16x16x32_bf16(afr, bfr, acc[n], 0, 0, 0);
      }
    }
    // wx store: D[row][col], col = lane&15 (+n*16+ch*128), row = fg*4+q
    const size_t rb = (size_t)strip * 16;
#pragma unroll
    for (int n = 0; n < 8; ++n) {
      int col = ch * 128 + n * 16 + fr;
#pragma unroll
      for (int q = 0; q < 4; ++q)
        wx[(rb + fg * 4 + q) * 256 + col] = acc[n][q];
    }
    // fused scores: this wave covers heads ch*4 .. ch*4+3
    const float as0 = a[fr], as1 = a[16 + fr];
    const float ad0 = a[32 + fr], ad1 = a[48 + fr];
#pragma unroll
    for (int j = 0; j < 4; ++j) {
      unsigned mp = 0u, md = 0u;
#pragma unroll
      for (int q = 0; q < 4; ++q) {
        float p = acc[2 * j][q] * as0 + acc[2 * j + 1][q] * as1;
        float d = acc[2 * j][q] * ad0 + acc[2 * j + 1][q] * ad1;
#pragma unroll
        for (int m = 1; m <= 8; m <<= 1) {
          p += __shfl_xor(p, m);
          d += __shfl_xor(d, m);
        }
        mp = max(mp, ordf(p));
        md = max(md, ordf(d));
        if (fr == 0) {
          size_t row = rb + fg * 4 + q;
          ssbf[row * 8 + ch * 4 + j] = f2bf(p);
          sdbf[row * 8 + ch * 4 + j] = f2bf(d);
        }
      }
      mp = max(mp, (unsigned)__shfl_xor((int)mp, 16));
      mp = max(mp, (unsigned)__shfl_xor((int)mp, 32));
      md = max(md, (unsigned)__shfl_xor((int)md, 16));
      md = max(md, (unsigned)__shfl_xor((int)md, 32));
      if (lane == 0) {
        atomicMax(&lmx[ch * 4 + j], mp);
        atomicMax(&lmx[8 + ch * 4 + j], md);
      }
    }
  }
  __syncthreads();
  if (tid < 16 && lmx[tid]) atomicMax(&mxbuf[tid], lmx[tid]);
}

// ---- LDS-privatized denom binning: block = (batch, head-half, src-range, slice) ----
__global__ __launch_bounds__(1024) void k_bin(const int* __restrict__ edge,
                                              const unsigned short* __restrict__ ssbf,
                                              const unsigned short* __restrict__ sdbf,
                                              const unsigned int* __restrict__ mxbuf,
                                              unsigned int* __restrict__ partial) {
  extern __shared__ unsigned int ldsu[];
  unsigned int* hist = ldsu;                      // [4][SEGR] u32
  uint2* stg = (uint2*)(ldsu + 4 * SEGR);         // [SEGR] 8-B src half-rows
  const int blk = blockIdx.x;                     // ((b*2+hq)*2+rq)*NSLICE + r
  const int r = blk & (NSLICE - 1);
  const int c = blk / NSLICE;
  const int rq = c & 1;
  const int hq = (c >> 1) & 1;
  const int b = c >> 2;
  const int tid = threadIdx.x;
  const int lo = rq * SEGR;
  for (int i = tid; i < 4 * SEGR; i += 1024) hist[i] = 0u;
  const unsigned short* ssb = ssbf + ((size_t)b * NN + lo) * 8 + hq * 4;
  for (int i = tid; i < SEGR; i += 1024) stg[i] = *(const uint2*)(ssb + (size_t)i * 8);
  __syncthreads();
  float MH[4];
#pragma unroll
  for (int j = 0; j < 4; ++j)
    MH[j] = fmaxf(unordf(mxbuf[hq * 4 + j]) + unordf(mxbuf[8 + hq * 4 + j]), 0.f);
  const int* eps = edge + (size_t)b * 2 * EE + r * ESL;
  const int* epd = eps + EE;
  const unsigned short* sdb = sdbf + (size_t)b * NN * 8 + hq * 4;
  for (int base = 0; base < ESL; base += UU * 1024) {
    int ls4[UU], dst4[UU];
    bool v4[UU];
#pragma unroll
    for (int u = 0; u < UU; ++u) {
      int i = base + tid + u * 1024;
      bool inb = i < ESL;
      int s = inb ? eps[i] : 0;
      dst4[u] = inb ? epd[i] : 0;
      int ls = s - lo;
      v4[u] = inb && ((unsigned)ls < (unsigned)SEGR);
      ls4[u] = ls;
    }
    uint2 du4[UU];
#pragma unroll
    for (int u = 0; u < UU; ++u)
      if (v4[u]) du4[u] = *(const uint2*)(sdb + (size_t)dst4[u] * 8);
#pragma unroll
    for (int u = 0; u < UU; ++u) {
      if (v4[u]) {
        uint2 su = stg[ls4[u]];
        float t0 = __uint_as_float(su.x << 16) + __uint_as_float(du4[u].x << 16);
        float t1 = __uint_as_float(su.x & 0xFFFF0000u) + __uint_as_float(du4[u].x & 0xFFFF0000u);
        float t2 = __uint_as_float(su.y << 16) + __uint_as_float(du4[u].y << 16);
        float t3 = __uint_as_float(su.y & 0xFFFF0000u) + __uint_as_float(du4[u].y & 0xFFFF0000u);
        t0 = t0 >= 0.f ? t0 : 0.2f * t0;
        t1 = t1 >= 0.f ? t1 : 0.2f * t1;
        t2 = t2 >= 0.f ? t2 : 0.2f * t2;
        t3 = t3 >= 0.f ? t3 : 0.2f * t3;
        atomicAdd(&hist[0 * SEGR + ls4[u]], (unsigned)(__expf(t0 - MH[0]) * SCALE + 0.5f));
        atomicAdd(&hist[1 * SEGR + ls4[u]], (unsigned)(__expf(t1 - MH[1]) * SCALE + 0.5f));
        atomicAdd(&hist[2 * SEGR + ls4[u]], (unsigned)(__expf(t2 - MH[2]) * SCALE + 0.5f));
        atomicAdd(&hist[3 * SEGR + ls4[u]], (unsigned)(__expf(t3 - MH[3]) * SCALE + 0.5f));
      }
    }
  }
  __syncthreads();
  f4* pout = (f4*)(partial + (size_t)blk * (4 * SEGR));
  const f4* lin = (const f4*)hist;
  for (int i = tid; i < SEGR; i += 1024) pout[i] = lin[i];
}

// ---- reduce NSLICE slice-partials (u32) -> denom (bf16 half-rows), exact int sums ----
__global__ __launch_bounds__(256) void k_reduce(const unsigned int* __restrict__ partial,
                                                unsigned short* __restrict__ dnbf) {
  const int t = blockIdx.x * 256 + threadIdx.x;   // BB*NHQ*NRQ*SEGR = 80000
  if (t >= BB * NHQ * NRQ * SEGR) return;
  const int ls = t % SEGR;
  const int c = t / SEGR;                         // ((b*2+hq)*2+rq)
  const unsigned int* pp = partial + (size_t)c * NSLICE * (4 * SEGR);
  unsigned long long s[4] = {0, 0, 0, 0};
#pragma unroll 4
  for (int r = 0; r < NSLICE; ++r)
#pragma unroll
    for (int h = 0; h < 4; ++h)
      s[h] += pp[(size_t)r * (4 * SEGR) + h * SEGR + ls];
  const int rq = c & 1, hq = (c >> 1) & 1, b = c >> 2;
  uint2 pk;
  pk.x = (unsigned)f2bf((float)s[0] * INVSC) | ((unsigned)f2bf((float)s[1] * INVSC) << 16);
  pk.y = (unsigned)f2bf((float)s[2] * INVSC) | ((unsigned)f2bf((float)s[3] * INVSC) << 16);
  *(uint2*)(dnbf + ((size_t)b * NN + rq * SEGR + ls) * 8 + hq * 4) = pk;
}

// ---------------- finalize: att = exp(el - M) / denom ----------------
__global__ __launch_bounds__(256) void k_fin(const int* __restrict__ edge,
                                             const unsigned short* __restrict__ ssbf,
                                             const unsigned short* __restrict__ sdbf,
                                             const unsigned short* __restrict__ dnbf,
                                             const unsigned int* __restrict__ mxbuf,
                                             float* __restrict__ att) {
  const int idx = blockIdx.x * 256 + threadIdx.x;
  const int b = idx / EE;
  const int e = idx - b * EE;
  const int src = edge[(size_t)b * 2 * EE + e];
  const int dst = edge[(size_t)b * 2 * EE + EE + e];
  const size_t seg = (size_t)b * NN + src;
  float MM[8];
#pragma unroll
  for (int j = 0; j < 8; ++j)
    MM[j] = fmaxf(unordf(mxbuf[j]) + unordf(mxbuf[8 + j]), 0.f);
  u16x8 ss = *(const u16x8*)(ssbf + seg * 8);
  u16x8 sd = *(const u16x8*)(sdbf + ((size_t)b * NN + dst) * 8);
  u16x8 dn = *(const u16x8*)(dnbf + seg * 8);
  f4 o0, o1;
#pragma unroll
  for (int j = 0; j < 4; ++j) {
    float t0 = bf2f(ss[j]) + bf2f(sd[j]);
    t0 = t0 >= 0.f ? t0 : 0.2f * t0;
    float t1 = bf2f(ss[4 + j]) + bf2f(sd[4 + j]);
    t1 = t1 >= 0.f ? t1 : 0.2f * t1;
    float n0 = __expf(t0 - MM[j]);
    float n1 = __expf(t1 - MM[4 + j]);
    o0[j] = n0 / fmaxf(bf2f(dn[j]), n0);
    o1[j] = n1 / fmaxf(bf2f(dn[4 + j]), n1);
  }
  f4* op = (f4*)(att + (size_t)idx * 8);
  op[0] = o0;
  op[1] = o1;
}

extern "C" void kernel_launch(void* const* d_in, const int* in_sizes, int n_in,
                              void* d_out, int out_size, void* d_ws, size_t ws_size,
                              hipStream_t stream) {
  const float* x = (const float*)d_in[0];
  const int* edge = (const int*)d_in[1];
  const float* W = (const float*)d_in[2];
  const float* a = (const float*)d_in[3];

  float* att = (float*)d_out;                       // (B,E,H) = 10,240,000 f32 = 40.96 MB
  float* wx = att + (size_t)BB * EE * HH;           // (B,N,256) = 10,240,000 f32

  // partial histograms live in the att output region (dead until k_fin):
  // 256 blocks * 80000 B = 20.48 MB < 40.96 MB.
  unsigned int* partial = (unsigned int*)att;

  char* ws = (char*)d_ws;
  unsigned short* Wt = (unsigned short*)ws;                 // 128 KiB
  unsigned short* ssbf = (unsigned short*)(ws + 131072);    // 320000 u16
  unsigned short* sdbf = ssbf + 320000;                     // 320000 u16
  unsigned short* dnbf = sdbf + 320000;                     // 320000 u16
  unsigned int* mxbuf = (unsigned int*)(dnbf + 320000);     // 16 u32

  const int gemmLds = 128 * 256 * 2 + 64;
  hipFuncSetAttribute((const void*)k_gemm, hipFuncAttributeMaxDynamicSharedMemorySize, gemmLds);
  hipFuncSetAttribute((const void*)k_bin, hipFuncAttributeMaxDynamicSharedMemorySize,
                      4 * SEGR * 4 + SEGR * 8);

  k_transpose<<<dim3(4, 4), 256, 0, stream>>>(W, Wt, mxbuf);
  k_gemm<<<626, 512, gemmLds, stream>>>(x, Wt, a, wx, ssbf, sdbf, mxbuf);
  k_bin<<<BB * NHQ * NRQ * NSLICE, 1024, 4 * SEGR * 4 + SEGR * 8, stream>>>(edge, ssbf, sdbf, mxbuf, partial);
  k_reduce<<<(BB * NHQ * NRQ * SEGR + 255) / 256, 256, 0, stream>>>(partial, dnbf);
  k_fin<<<5000, 256, 0, stream>>>(edge, ssbf, sdbf, dnbf, mxbuf, att);
}